// Round 1
// baseline (930.141 us; speedup 1.0000x reference)
//
#include <hip/hip_runtime.h>
#include <stdint.h>

// Problem constants
#define S_LEN 2048
#define NH    24
#define HD    128
#define HID   3072    // NH*HD
#define IPS   512
#define IPD   1152

using f16   = __fp16;
using f16x4 = __fp16 __attribute__((ext_vector_type(4)));
using f16x8 = __fp16 __attribute__((ext_vector_type(8)));
using f32x4 = float  __attribute__((ext_vector_type(4)));

// ---------------------------------------------------------------------------
// async global->LDS, 16B per lane. LDS dest is wave-uniform base + lane*16.
__device__ __forceinline__ void glds16(const f16* g, f16* l) {
  __builtin_amdgcn_global_load_lds((const __attribute__((address_space(1))) void*)g,
                                   (__attribute__((address_space(3))) void*)l,
                                   16, 0, 0);
}

// ---------------------------------------------------------------------------
// fp32 -> fp16 cast, 4 elems/thread (all sizes divisible by 1024)
__global__ void k_cvt(const float* __restrict__ src, f16* __restrict__ dst, int n4) {
  int i = blockIdx.x * 256 + threadIdx.x;
  if (i >= n4) return;
  float4 v = ((const float4*)src)[i];
  f16x4 o;
  o.x = (f16)v.x; o.y = (f16)v.y; o.z = (f16)v.z; o.w = (f16)v.w;
  ((f16x4*)dst)[i] = o;
}

// ---------------------------------------------------------------------------
// NT GEMM: C[M,N] = A[M,K] @ B[N,K]^T + bias.  A,B fp16 K-contiguous.
// 128x128 tile, BK=32, 256 thr = 4 waves (2x2), 16x16x32 MFMA.
// blockIdx.z selects one of up to 3 (B, bias, C) triples (QKV fusion).
__global__ __launch_bounds__(256) void k_gemm_nt(
    const f16* __restrict__ A,
    const f16* __restrict__ B0, const f16* __restrict__ B1, const f16* __restrict__ B2,
    const float* __restrict__ bias0, const float* __restrict__ bias1, const float* __restrict__ bias2,
    void* __restrict__ C0, void* __restrict__ C1, void* __restrict__ C2,
    int M, int N, int K, int out_f32)
{
  const int z = blockIdx.z;
  const f16*   B    = (z == 0) ? B0 : (z == 1) ? B1 : B2;
  const float* bias = (z == 0) ? bias0 : (z == 1) ? bias1 : bias2;
  void*        Cv   = (z == 0) ? C0 : (z == 1) ? C1 : C2;

  __shared__ f16 As[128 * 32];
  __shared__ f16 Bs[128 * 32];

  const int tid  = threadIdx.x;
  const int w    = tid >> 6, l = tid & 63;
  const int quad = l >> 4,  l16 = l & 15;
  const int bm = blockIdx.y * 128, bn = blockIdx.x * 128;
  const int wm = (w >> 1) * 64,    wn = (w & 1) * 64;

  f32x4 acc[4][4] = {};

  // staging: each wave stages 32 rows of A and of B (2 glds instrs each).
  // instr covers 16 rows: lane -> row l>>2, k-chunk (l&3)*8
  const int r0 = w * 32;
  const f16* Ag = A + (bm + r0 + (l >> 2)) * K + (l & 3) * 8;
  const f16* Bg = B + (bn + r0 + (l >> 2)) * K + (l & 3) * 8;
  f16* lA0 = &As[r0 * 32];
  f16* lA1 = &As[(r0 + 16) * 32];
  f16* lB0 = &Bs[r0 * 32];
  f16* lB1 = &Bs[(r0 + 16) * 32];
  const int kstride16 = 16 * K;

  for (int k0 = 0; k0 < K; k0 += 32) {
    glds16(Ag + k0,             lA0);
    glds16(Ag + kstride16 + k0, lA1);
    glds16(Bg + k0,             lB0);
    glds16(Bg + kstride16 + k0, lB1);
    __syncthreads();   // waits vmcnt(0) then barrier

    f16x8 af[4], bf[4];
#pragma unroll
    for (int i = 0; i < 4; i++)
      af[i] = *(const f16x8*)&As[(wm + i * 16 + l16) * 32 + quad * 8];
#pragma unroll
    for (int j = 0; j < 4; j++)
      bf[j] = *(const f16x8*)&Bs[(wn + j * 16 + l16) * 32 + quad * 8];
#pragma unroll
    for (int i = 0; i < 4; i++)
#pragma unroll
      for (int j = 0; j < 4; j++)
        acc[i][j] = __builtin_amdgcn_mfma_f32_16x16x32_f16(af[i], bf[j], acc[i][j], 0, 0, 0);
    __syncthreads();
  }

  float bv[4];
#pragma unroll
  for (int j = 0; j < 4; j++) bv[j] = bias[bn + wn + j * 16 + l16];

#pragma unroll
  for (int i = 0; i < 4; i++) {
    const int row0 = bm + wm + i * 16 + quad * 4;
#pragma unroll
    for (int j = 0; j < 4; j++) {
      const int col = bn + wn + j * 16 + l16;
#pragma unroll
      for (int r = 0; r < 4; r++) {
        float v = acc[i][j][r] + bv[j];
        if (out_f32) ((float*)Cv)[(row0 + r) * N + col] = v;
        else         ((f16*)Cv)[(row0 + r) * N + col] = (f16)v;
      }
    }
  }
}

// ---------------------------------------------------------------------------
// RoPE on [S][HID] (layout [s][h*128+d]); sin/cos are [S][64].
__global__ void k_rope(const f16* __restrict__ x, const float* __restrict__ snp,
                       const float* __restrict__ csp, f16* __restrict__ out, int total) {
  int idx = blockIdx.x * 256 + threadIdx.x;
  if (idx >= total) return;
  int s = idx / HID;
  int c = idx - s * HID;
  int d = c & (HD - 1);
  float v = (float)x[idx];
  float r;
  if (d < 64) {
    float cs = csp[s * 64 + d], sn = snp[s * 64 + d];
    if (d < 32) r = v * cs - (float)x[idx + 32] * sn;
    else        r = v * cs + (float)x[idx - 32] * sn;
  } else {
    r = v;
  }
  out[idx] = (f16)r;
}

// ---------------------------------------------------------------------------
// RMSNorm per 128-elem head row + *D^-0.5:  out = scale[d] * x / (rms+eps) * D^-0.5
__global__ void k_rmsnorm(const f16* __restrict__ x, const float* __restrict__ scale,
                          f16* __restrict__ out, int rows) {
  int gw = (blockIdx.x * 256 + threadIdx.x) >> 6;
  int l  = threadIdx.x & 63;
  if (gw >= rows) return;
  int base = gw * HD;
  float a = (float)x[base + 2 * l];
  float b = (float)x[base + 2 * l + 1];
  float ss = a * a + b * b;
#pragma unroll
  for (int off = 32; off >= 1; off >>= 1) ss += __shfl_xor(ss, off, 64);
  float rms = sqrtf(ss * (1.0f / HD));
  float inv = 0.08838834764831845f / (rms + 1e-6f);   // D^-0.5 / (rms+eps)
  out[base + 2 * l]     = (f16)(a * scale[2 * l] * inv);
  out[base + 2 * l + 1] = (f16)(b * scale[2 * l + 1] * inv);
}

// ---------------------------------------------------------------------------
// Transpose V: vt[h][d][t] = v[t][h*128+d]
__global__ void k_transpose(const f16* __restrict__ v, f16* __restrict__ vt, int T) {
  __shared__ f16 tile[32][33];
  int t0 = blockIdx.x * 32, d0 = blockIdx.y * 32, h = blockIdx.z;
  int x = threadIdx.x, y = threadIdx.y;
#pragma unroll
  for (int r = 0; r < 32; r += 8)
    tile[y + r][x] = v[(t0 + y + r) * HID + h * HD + d0 + x];
  __syncthreads();
#pragma unroll
  for (int r = 0; r < 32; r += 8)
    vt[(h * HD + d0 + y + r) * T + t0 + x] = tile[x][y + r];
}

// ---------------------------------------------------------------------------
// Flash attention, one block = (q-block of 128 rows, head). 4 waves x 32 q-rows.
// BT=64. Q frags in regs; K/V B-frags direct from global; P via per-wave LDS.
// mode 0: Out = softmax(QK^T)V (fp16).  mode 1: Out = prev + softmax(QK^T)V.
__global__ __launch_bounds__(256, 2) void k_flash(
    const f16* __restrict__ Q, const f16* __restrict__ Km,
    const f16* __restrict__ Vt, const f16* __restrict__ prev,
    f16* __restrict__ Out, int T, int mode)
{
  __shared__ f16 Ps[4][32 * 72];   // per-wave P tile [32 q][64 t], ld=72

  const int h    = blockIdx.y;
  const int tid  = threadIdx.x, w = tid >> 6, l = tid & 63;
  const int quad = l >> 4, l16 = l & 15;
  const int qr   = blockIdx.x * 128 + w * 32;

  // Q fragments (A operand): lane holds A[m=l16][k=quad*8+j] per 16x32 chunk
  f16x8 qf[2][4];
#pragma unroll
  for (int mt = 0; mt < 2; mt++)
#pragma unroll
    for (int kq = 0; kq < 4; kq++)
      qf[mt][kq] = *(const f16x8*)(Q + (qr + mt * 16 + l16) * HID + h * HD + kq * 32 + quad * 8);

  f32x4 o[2][8] = {};
  float m_run[8], l_run[8];
#pragma unroll
  for (int i = 0; i < 8; i++) { m_run[i] = -1e30f; l_run[i] = 0.f; }

  f16* myP = &Ps[w][0];

  for (int t0 = 0; t0 < T; t0 += 64) {
    // ---- S = Q K^T ----
    f32x4 s[2][4] = {};
#pragma unroll
    for (int kq = 0; kq < 4; kq++) {
      f16x8 kf[4];
#pragma unroll
      for (int jn = 0; jn < 4; jn++)
        kf[jn] = *(const f16x8*)(Km + (t0 + jn * 16 + l16) * HID + h * HD + kq * 32 + quad * 8);
#pragma unroll
      for (int mt = 0; mt < 2; mt++)
#pragma unroll
        for (int jn = 0; jn < 4; jn++)
          s[mt][jn] = __builtin_amdgcn_mfma_f32_16x16x32_f16(qf[mt][kq], kf[jn], s[mt][jn], 0, 0, 0);
    }

    // ---- online softmax (rows = quad*4+r within each 16-row mt tile) ----
#pragma unroll
    for (int mt = 0; mt < 2; mt++) {
#pragma unroll
      for (int r = 0; r < 4; r++) {
        float mx = fmaxf(fmaxf(s[mt][0][r], s[mt][1][r]), fmaxf(s[mt][2][r], s[mt][3][r]));
        mx = fmaxf(mx, __shfl_xor(mx, 1, 64));
        mx = fmaxf(mx, __shfl_xor(mx, 2, 64));
        mx = fmaxf(mx, __shfl_xor(mx, 4, 64));
        mx = fmaxf(mx, __shfl_xor(mx, 8, 64));
        const int ri = mt * 4 + r;
        float mn = fmaxf(m_run[ri], mx);
        float al = __expf(m_run[ri] - mn);
        m_run[ri] = mn;
        float p0 = __expf(s[mt][0][r] - mn);
        float p1 = __expf(s[mt][1][r] - mn);
        float p2 = __expf(s[mt][2][r] - mn);
        float p3 = __expf(s[mt][3][r] - mn);
        s[mt][0][r] = p0; s[mt][1][r] = p1; s[mt][2][r] = p2; s[mt][3][r] = p3;
        l_run[ri] = l_run[ri] * al + (p0 + p1 + p2 + p3);   // lane-partial; reduced at end
#pragma unroll
        for (int jd = 0; jd < 8; jd++) o[mt][jd][r] *= al;
      }
    }

    // ---- P -> LDS (C-layout -> A-layout round trip) ----
#pragma unroll
    for (int mt = 0; mt < 2; mt++)
#pragma unroll
      for (int jn = 0; jn < 4; jn++)
#pragma unroll
        for (int r = 0; r < 4; r++)
          myP[(mt * 16 + quad * 4 + r) * 72 + jn * 16 + l16] = (f16)s[mt][jn][r];
    __syncthreads();

    // ---- O += P V ----
#pragma unroll
    for (int ks = 0; ks < 2; ks++) {
      f16x8 pf[2];
#pragma unroll
      for (int mt = 0; mt < 2; mt++)
        pf[mt] = *(const f16x8*)&myP[(mt * 16 + l16) * 72 + ks * 32 + quad * 8];
      f16x8 vf[8];
#pragma unroll
      for (int jd = 0; jd < 8; jd++)
        vf[jd] = *(const f16x8*)(Vt + (h * HD + jd * 16 + l16) * T + t0 + ks * 32 + quad * 8);
#pragma unroll
      for (int jd = 0; jd < 8; jd++)
#pragma unroll
        for (int mt = 0; mt < 2; mt++)
          o[mt][jd] = __builtin_amdgcn_mfma_f32_16x16x32_f16(pf[mt], vf[jd], o[mt][jd], 0, 0, 0);
    }
  }

  // reduce row-sums across the 16 lanes sharing each row
#pragma unroll
  for (int i = 0; i < 8; i++) {
    float v = l_run[i];
    v += __shfl_xor(v, 1, 64);
    v += __shfl_xor(v, 2, 64);
    v += __shfl_xor(v, 4, 64);
    v += __shfl_xor(v, 8, 64);
    l_run[i] = v;
  }

#pragma unroll
  for (int mt = 0; mt < 2; mt++)
#pragma unroll
    for (int jd = 0; jd < 8; jd++)
#pragma unroll
      for (int r = 0; r < 4; r++) {
        int row = qr + mt * 16 + quad * 4 + r;
        int col = h * HD + jd * 16 + l16;
        float val = o[mt][jd][r] / l_run[mt * 4 + r];
        if (mode) val += (float)prev[row * HID + col];
        Out[row * HID + col] = (f16)val;
      }
}

// ---------------------------------------------------------------------------
extern "C" void kernel_launch(void* const* d_in, const int* in_sizes, int n_in,
                              void* d_out, int out_size, void* d_ws, size_t ws_size,
                              hipStream_t stream) {
  const float* hs   = (const float*)d_in[0];
  const float* ip   = (const float*)d_in[1];
  const float* snp  = (const float*)d_in[2];
  const float* csp  = (const float*)d_in[3];
  const float* Wq   = (const float*)d_in[4];
  const float* bq   = (const float*)d_in[5];
  const float* Wk   = (const float*)d_in[6];
  const float* bk   = (const float*)d_in[7];
  const float* Wv   = (const float*)d_in[8];
  const float* bv   = (const float*)d_in[9];
  const float* Wo   = (const float*)d_in[10];
  const float* bo   = (const float*)d_in[11];
  const float* Wkip = (const float*)d_in[12];
  const float* bkip = (const float*)d_in[13];
  const float* Wvip = (const float*)d_in[14];
  const float* bvip = (const float*)d_in[15];
  const float* qs   = (const float*)d_in[16];
  const float* ks   = (const float*)d_in[17];
  float* out = (float*)d_out;

  // workspace layout (fp16 element offsets)
  const long n_hs = 6291456;            // 2048*3072
  const long nW   = 9437184;            // 3072*3072
  const long n_ip = 589824;             // 512*1152
  const long nWip = 3538944;            // 3072*1152
  const long n_kip = 1572864;           // 512*3072

  const long o_hs   = 0;
  const long o_Wq   = o_hs + n_hs;
  const long o_Wk   = o_Wq + nW;
  const long o_Wv   = o_Wk + nW;
  const long o_Wo   = o_Wv + nW;
  const long o_ip   = o_Wo + nW;
  const long o_Wkip = o_ip + n_ip;
  const long o_Wvip = o_Wkip + nWip;
  const long o_q    = o_Wvip + nWip;
  const long o_k    = o_q + n_hs;
  const long o_v    = o_k + n_hs;
  const long o_kip  = o_v + n_hs;
  const long o_vip  = o_kip + n_kip;
  const long o_qrot = o_vip + n_kip;
  const long o_krot = o_qrot + n_hs;
  const long o_qnorm= o_krot + n_hs;
  const long o_kipn = o_qnorm + n_hs;
  const long o_vtip = o_kipn + n_kip;
  // safe reuses (lifetimes verified):
  const long o_vt   = o_hs;   // hs_f16 dead after QKV GEMMs
  const long o_out1 = o_k;    // k dead after rope-k
  const long o_attn = o_q;    // q dead after rope-q + rmsnorm-q

  f16* WS = (f16*)d_ws;
  auto P = [&](long off) { return WS + off; };

  // 1) fp32 -> fp16 conversions
  k_cvt<<<dim3(n_hs / 1024), 256, 0, stream>>>(hs,   P(o_hs),   n_hs / 4);
  k_cvt<<<dim3(n_ip / 1024), 256, 0, stream>>>(ip,   P(o_ip),   n_ip / 4);
  k_cvt<<<dim3(nW / 1024),   256, 0, stream>>>(Wq,   P(o_Wq),   nW / 4);
  k_cvt<<<dim3(nW / 1024),   256, 0, stream>>>(Wk,   P(o_Wk),   nW / 4);
  k_cvt<<<dim3(nW / 1024),   256, 0, stream>>>(Wv,   P(o_Wv),   nW / 4);
  k_cvt<<<dim3(nW / 1024),   256, 0, stream>>>(Wo,   P(o_Wo),   nW / 4);
  k_cvt<<<dim3(nWip / 1024), 256, 0, stream>>>(Wkip, P(o_Wkip), nWip / 4);
  k_cvt<<<dim3(nWip / 1024), 256, 0, stream>>>(Wvip, P(o_Wvip), nWip / 4);

  // 2) projections
  k_gemm_nt<<<dim3(24, 16, 3), 256, 0, stream>>>(P(o_hs),
      P(o_Wq), P(o_Wk), P(o_Wv), bq, bk, bv,
      P(o_q), P(o_k), P(o_v), 2048, 3072, 3072, 0);
  k_gemm_nt<<<dim3(24, 4, 2), 256, 0, stream>>>(P(o_ip),
      P(o_Wkip), P(o_Wvip), P(o_Wvip), bkip, bvip, bvip,
      P(o_kip), P(o_vip), P(o_vip), 512, 3072, 1152, 0);

  // 3) prep: RoPE, RMSNorm, V transpose
  k_rope<<<dim3(n_hs / 256), 256, 0, stream>>>(P(o_q), snp, csp, P(o_qrot), (int)n_hs);
  k_rope<<<dim3(n_hs / 256), 256, 0, stream>>>(P(o_k), snp, csp, P(o_krot), (int)n_hs);
  k_rmsnorm<<<dim3(49152 * 64 / 256), 256, 0, stream>>>(P(o_q),   qs, P(o_qnorm), 49152);
  k_rmsnorm<<<dim3(12288 * 64 / 256), 256, 0, stream>>>(P(o_kip), ks, P(o_kipn), 12288);
  k_transpose<<<dim3(64, 4, 24), dim3(32, 8), 0, stream>>>(P(o_v),   P(o_vt),   2048);
  k_transpose<<<dim3(16, 4, 24), dim3(32, 8), 0, stream>>>(P(o_vip), P(o_vtip), 512);

  // 4) attention: self stream then IP stream (adds into result)
  k_flash<<<dim3(16, 24), 256, 0, stream>>>(P(o_qrot),  P(o_krot), P(o_vt),   nullptr,   P(o_out1), 2048, 0);
  k_flash<<<dim3(16, 24), 256, 0, stream>>>(P(o_qnorm), P(o_kipn), P(o_vtip), P(o_out1), P(o_attn),  512, 1);

  // 5) output projection -> fp32 d_out
  k_gemm_nt<<<dim3(24, 16, 1), 256, 0, stream>>>(P(o_attn),
      P(o_Wo), P(o_Wo), P(o_Wo), bo, bo, bo,
      out, out, out, 2048, 3072, 3072, 1);
}

// Round 2
// 756.976 us; speedup vs baseline: 1.2288x; 1.2288x over previous
//
#include <hip/hip_runtime.h>
#include <stdint.h>

// Problem constants
#define S_LEN 2048
#define NH    24
#define HD    128
#define HID   3072    // NH*HD
#define IPS   512
#define IPD   1152

using f16   = __fp16;
using f16x4 = __fp16 __attribute__((ext_vector_type(4)));
using f16x8 = __fp16 __attribute__((ext_vector_type(8)));
using f32x4 = float  __attribute__((ext_vector_type(4)));

// ---------------------------------------------------------------------------
// async global->LDS, 16B per lane. LDS dest is wave-uniform base + lane*16.
__device__ __forceinline__ void glds16(const f16* g, f16* l) {
  __builtin_amdgcn_global_load_lds((const __attribute__((address_space(1))) void*)g,
                                   (__attribute__((address_space(3))) void*)l,
                                   16, 0, 0);
}

// ---------------------------------------------------------------------------
// fp32 -> fp16 cast, 4 elems/thread
__global__ void k_cvt(const float* __restrict__ src, f16* __restrict__ dst, int n4) {
  int i = blockIdx.x * 256 + threadIdx.x;
  if (i >= n4) return;
  float4 v = ((const float4*)src)[i];
  f16x4 o;
  o.x = (f16)v.x; o.y = (f16)v.y; o.z = (f16)v.z; o.w = (f16)v.w;
  ((f16x4*)dst)[i] = o;
}

// ---------------------------------------------------------------------------
// NT GEMM: C[M,N] = A[M,K] @ B[N,K]^T + bias. 128x128 tile, BK=32, 4 waves.
__global__ __launch_bounds__(256) void k_gemm_nt(
    const f16* __restrict__ A,
    const f16* __restrict__ B0, const f16* __restrict__ B1, const f16* __restrict__ B2,
    const float* __restrict__ bias0, const float* __restrict__ bias1, const float* __restrict__ bias2,
    void* __restrict__ C0, void* __restrict__ C1, void* __restrict__ C2,
    int M, int N, int K, int out_f32)
{
  const int z = blockIdx.z;
  const f16*   B    = (z == 0) ? B0 : (z == 1) ? B1 : B2;
  const float* bias = (z == 0) ? bias0 : (z == 1) ? bias1 : bias2;
  void*        Cv   = (z == 0) ? C0 : (z == 1) ? C1 : C2;

  __shared__ f16 As[128 * 32];
  __shared__ f16 Bs[128 * 32];

  const int tid  = threadIdx.x;
  const int w    = tid >> 6, l = tid & 63;
  const int quad = l >> 4,  l16 = l & 15;
  const int bm = blockIdx.y * 128, bn = blockIdx.x * 128;
  const int wm = (w >> 1) * 64,    wn = (w & 1) * 64;

  f32x4 acc[4][4] = {};

  const int r0 = w * 32;
  const f16* Ag = A + (bm + r0 + (l >> 2)) * K + (l & 3) * 8;
  const f16* Bg = B + (bn + r0 + (l >> 2)) * K + (l & 3) * 8;
  f16* lA0 = &As[r0 * 32];
  f16* lA1 = &As[(r0 + 16) * 32];
  f16* lB0 = &Bs[r0 * 32];
  f16* lB1 = &Bs[(r0 + 16) * 32];
  const int kstride16 = 16 * K;

  for (int k0 = 0; k0 < K; k0 += 32) {
    glds16(Ag + k0,             lA0);
    glds16(Ag + kstride16 + k0, lA1);
    glds16(Bg + k0,             lB0);
    glds16(Bg + kstride16 + k0, lB1);
    __syncthreads();

    f16x8 af[4], bf[4];
#pragma unroll
    for (int i = 0; i < 4; i++)
      af[i] = *(const f16x8*)&As[(wm + i * 16 + l16) * 32 + quad * 8];
#pragma unroll
    for (int j = 0; j < 4; j++)
      bf[j] = *(const f16x8*)&Bs[(wn + j * 16 + l16) * 32 + quad * 8];
#pragma unroll
    for (int i = 0; i < 4; i++)
#pragma unroll
      for (int j = 0; j < 4; j++)
        acc[i][j] = __builtin_amdgcn_mfma_f32_16x16x32_f16(af[i], bf[j], acc[i][j], 0, 0, 0);
    __syncthreads();
  }

  float bv[4];
#pragma unroll
  for (int j = 0; j < 4; j++) bv[j] = bias[bn + wn + j * 16 + l16];

#pragma unroll
  for (int i = 0; i < 4; i++) {
    const int row0 = bm + wm + i * 16 + quad * 4;
#pragma unroll
    for (int j = 0; j < 4; j++) {
      const int col = bn + wn + j * 16 + l16;
#pragma unroll
      for (int r = 0; r < 4; r++) {
        float v = acc[i][j][r] + bv[j];
        if (out_f32) ((float*)Cv)[(row0 + r) * N + col] = v;
        else         ((f16*)Cv)[(row0 + r) * N + col] = (f16)v;
      }
    }
  }
}

// ---------------------------------------------------------------------------
// RoPE on [S][HID]; sin/cos [S][64]. (for Q only now)
__global__ void k_rope(const f16* __restrict__ x, const float* __restrict__ snp,
                       const float* __restrict__ csp, f16* __restrict__ out, int total) {
  int idx = blockIdx.x * 256 + threadIdx.x;
  if (idx >= total) return;
  int s = idx / HID;
  int c = idx - s * HID;
  int d = c & (HD - 1);
  float v = (float)x[idx];
  float r;
  if (d < 64) {
    float cs = csp[s * 64 + d], sn = snp[s * 64 + d];
    if (d < 32) r = v * cs - (float)x[idx + 32] * sn;
    else        r = v * cs + (float)x[idx - 32] * sn;
  } else {
    r = v;
  }
  out[idx] = (f16)r;
}

// ---------------------------------------------------------------------------
// RMSNorm per 128-elem head row + *D^-0.5
__global__ void k_rmsnorm(const f16* __restrict__ x, const float* __restrict__ scale,
                          f16* __restrict__ out, int rows) {
  int gw = (blockIdx.x * 256 + threadIdx.x) >> 6;
  int l  = threadIdx.x & 63;
  if (gw >= rows) return;
  int base = gw * HD;
  float a = (float)x[base + 2 * l];
  float b = (float)x[base + 2 * l + 1];
  float ss = a * a + b * b;
#pragma unroll
  for (int off = 32; off >= 1; off >>= 1) ss += __shfl_xor(ss, off, 64);
  float rms = sqrtf(ss * (1.0f / HD));
  float inv = 0.08838834764831845f / (rms + 1e-6f);
  out[base + 2 * l]     = (f16)(a * scale[2 * l] * inv);
  out[base + 2 * l + 1] = (f16)(b * scale[2 * l + 1] * inv);
}

// ---------------------------------------------------------------------------
// Pack K [S][HID] -> B-fragment order:
// dst chunk f16x8 at (((h*(T/16) + t/16)*4 + d/32)*64 + ((d>>3)&3)*16 + (t&15))*8
__global__ void k_kpack(const f16* __restrict__ src, f16* __restrict__ dst, int T, int nchunk) {
  int i = blockIdx.x * 256 + threadIdx.x;
  if (i >= nchunk) return;
  int d8 = i % 384;          // chunk within row
  int t  = i / 384;
  int h  = d8 >> 4;
  int d  = (d8 & 15) * 8;
  f16x8 x = *(const f16x8*)(src + (long)i * 8);
  long off = ((((long)h * (T >> 4) + (t >> 4)) * 4 + (d >> 5)) * 64 + ((d >> 3) & 3) * 16 + (t & 15)) * 8;
  *(f16x8*)(dst + off) = x;
}

// Same pack, with RoPE fused (reads pre-rope K)
__global__ void k_krope_pack(const f16* __restrict__ src, const float* __restrict__ snp,
                             const float* __restrict__ csp, f16* __restrict__ dst,
                             int T, int nchunk) {
  int i = blockIdx.x * 256 + threadIdx.x;
  if (i >= nchunk) return;
  int d8 = i % 384;
  int t  = i / 384;
  int h  = d8 >> 4;
  int d  = (d8 & 15) * 8;
  f16x8 x = *(const f16x8*)(src + (long)i * 8);
  f16x8 o;
  if (d < 64) {
    f16x8 p = (d < 32) ? *(const f16x8*)(src + (long)i * 8 + 32)
                       : *(const f16x8*)(src + (long)i * 8 - 32);
    float sgn = (d < 32) ? -1.0f : 1.0f;
#pragma unroll
    for (int j = 0; j < 8; j++) {
      float cs = csp[t * 64 + d + j], sn = snp[t * 64 + d + j];
      o[j] = (f16)((float)x[j] * cs + sgn * (float)p[j] * sn);
    }
  } else {
    o = x;
  }
  long off = ((((long)h * (T >> 4) + (t >> 4)) * 4 + (d >> 5)) * 64 + ((d >> 3) & 3) * 16 + (t & 15)) * 8;
  *(f16x8*)(dst + off) = o;
}

// ---------------------------------------------------------------------------
// Pack V [T][HID] -> PV B-fragment order (transposed: frag j indexes t):
// dst chunk f16x8 at ((((h*(T/64)+tb)*2+ks)*8+jd)*64 + quad*16 + l16)*8,
//   elements j: V[t0+ks*32+quad*8+j][h*128 + jd*16+l16]
__global__ __launch_bounds__(256) void k_vpack(const f16* __restrict__ v, f16* __restrict__ dst, int T) {
  __shared__ f16 Ts[128 * 72];   // [d][t], ld=72
  int h = blockIdx.y, tb = blockIdx.x, t0 = tb * 64;
  int tid = threadIdx.x;
  // stage + transpose: thread reads 4 chunks of row r
  int r = tid >> 2, c4 = tid & 3;
#pragma unroll
  for (int cc = 0; cc < 4; cc++) {
    int ch = c4 * 4 + cc;
    f16x8 x = *(const f16x8*)(v + (long)(t0 + r) * HID + h * HD + ch * 8);
#pragma unroll
    for (int j = 0; j < 8; j++)
      Ts[(ch * 8 + j) * 72 + r] = x[j];
  }
  __syncthreads();
  int l16 = tid & 15, jd = (tid >> 4) & 7, ks = tid >> 7;
#pragma unroll
  for (int quad = 0; quad < 4; quad++) {
    f16x8 x = *(const f16x8*)&Ts[(jd * 16 + l16) * 72 + ks * 32 + quad * 8];
    long off = ((((long)h * (T >> 6) + tb) * 2 + ks) * 8 + jd) * 512 + (quad * 16 + l16) * 8;
    *(f16x8*)(dst + off) = x;
  }
}

// ---------------------------------------------------------------------------
// Flash attention with split-T. Block = (128 q-rows, head, T-split).
// Writes UNNORMALIZED max-shifted partial O (f16) + per-row (m,l) float2.
__global__ __launch_bounds__(256) void k_flash2(
    const f16* __restrict__ Q, const f16* __restrict__ Kp, const f16* __restrict__ Vp,
    f16* __restrict__ Opart, long part_stride, float2* __restrict__ ml, int p0,
    int T, int Tc)
{
  __shared__ f16 Ps[4][32 * 72];   // per-wave P tile, no barrier needed

  const int h    = blockIdx.y;
  const int sp   = blockIdx.z;
  const int tid  = threadIdx.x, w = tid >> 6, l = tid & 63;
  const int quad = l >> 4, l16 = l & 15;
  const int qr   = blockIdx.x * 128 + w * 32;
  const int Tt16 = T >> 4, Tt64 = T >> 6;

  f16x8 qf[2][4];
#pragma unroll
  for (int mt = 0; mt < 2; mt++)
#pragma unroll
    for (int kq = 0; kq < 4; kq++)
      qf[mt][kq] = *(const f16x8*)(Q + (long)(qr + mt * 16 + l16) * HID + h * HD + kq * 32 + quad * 8);

  f32x4 o[2][8] = {};
  float m_run[8], l_run[8];
#pragma unroll
  for (int i = 0; i < 8; i++) { m_run[i] = -1e30f; l_run[i] = 0.f; }

  f16* myP = &Ps[w][0];
  const int t_begin = sp * Tc, t_end = t_begin + Tc;

  for (int t0 = t_begin; t0 < t_end; t0 += 64) {
    // ---- S = Q K^T (Kp coalesced B-frags) ----
    f32x4 s[2][4] = {};
#pragma unroll
    for (int kq = 0; kq < 4; kq++) {
      f16x8 kf[4];
#pragma unroll
      for (int jn = 0; jn < 4; jn++)
        kf[jn] = *(const f16x8*)(Kp + (((long)(h * Tt16 + (t0 >> 4) + jn) * 4 + kq) * 64 + l) * 8);
#pragma unroll
      for (int mt = 0; mt < 2; mt++)
#pragma unroll
        for (int jn = 0; jn < 4; jn++)
          s[mt][jn] = __builtin_amdgcn_mfma_f32_16x16x32_f16(qf[mt][kq], kf[jn], s[mt][jn], 0, 0, 0);
    }

    // ---- online softmax ----
#pragma unroll
    for (int mt = 0; mt < 2; mt++) {
#pragma unroll
      for (int r = 0; r < 4; r++) {
        float mx = fmaxf(fmaxf(s[mt][0][r], s[mt][1][r]), fmaxf(s[mt][2][r], s[mt][3][r]));
        mx = fmaxf(mx, __shfl_xor(mx, 1, 64));
        mx = fmaxf(mx, __shfl_xor(mx, 2, 64));
        mx = fmaxf(mx, __shfl_xor(mx, 4, 64));
        mx = fmaxf(mx, __shfl_xor(mx, 8, 64));
        const int ri = mt * 4 + r;
        float mn = fmaxf(m_run[ri], mx);
        float al = __expf(m_run[ri] - mn);
        m_run[ri] = mn;
        float p0v = __expf(s[mt][0][r] - mn);
        float p1v = __expf(s[mt][1][r] - mn);
        float p2v = __expf(s[mt][2][r] - mn);
        float p3v = __expf(s[mt][3][r] - mn);
        s[mt][0][r] = p0v; s[mt][1][r] = p1v; s[mt][2][r] = p2v; s[mt][3][r] = p3v;
        l_run[ri] = l_run[ri] * al + (p0v + p1v + p2v + p3v);
#pragma unroll
        for (int jd = 0; jd < 8; jd++) o[mt][jd][r] *= al;
      }
    }

    // ---- P -> per-wave LDS (C-layout -> A-layout), no barrier ----
#pragma unroll
    for (int mt = 0; mt < 2; mt++)
#pragma unroll
      for (int jn = 0; jn < 4; jn++)
#pragma unroll
        for (int r = 0; r < 4; r++)
          myP[(mt * 16 + quad * 4 + r) * 72 + jn * 16 + l16] = (f16)s[mt][jn][r];

    // ---- O += P V (Vp coalesced B-frags) ----
#pragma unroll
    for (int ks = 0; ks < 2; ks++) {
      f16x8 pf[2];
#pragma unroll
      for (int mt = 0; mt < 2; mt++)
        pf[mt] = *(const f16x8*)&myP[(mt * 16 + l16) * 72 + ks * 32 + quad * 8];
      f16x8 vf[8];
#pragma unroll
      for (int jd = 0; jd < 8; jd++)
        vf[jd] = *(const f16x8*)(Vp + ((((long)(h * Tt64 + (t0 >> 6)) * 2 + ks) * 8 + jd) * 64 + l) * 8);
#pragma unroll
      for (int jd = 0; jd < 8; jd++)
#pragma unroll
        for (int mt = 0; mt < 2; mt++)
          o[mt][jd] = __builtin_amdgcn_mfma_f32_16x16x32_f16(pf[mt], vf[jd], o[mt][jd], 0, 0, 0);
    }
  }

  // reduce row-sums across 16 lanes per row
#pragma unroll
  for (int i = 0; i < 8; i++) {
    float v = l_run[i];
    v += __shfl_xor(v, 1, 64);
    v += __shfl_xor(v, 2, 64);
    v += __shfl_xor(v, 4, 64);
    v += __shfl_xor(v, 8, 64);
    l_run[i] = v;
  }

  f16* Od = Opart + (long)sp * part_stride;
#pragma unroll
  for (int mt = 0; mt < 2; mt++)
#pragma unroll
    for (int jd = 0; jd < 8; jd++)
#pragma unroll
      for (int r = 0; r < 4; r++) {
        int row = qr + mt * 16 + quad * 4 + r;
        int col = h * HD + jd * 16 + l16;
        Od[(long)row * HID + col] = (f16)o[mt][jd][r];
      }
  if (l16 == 0) {
#pragma unroll
    for (int mt = 0; mt < 2; mt++)
#pragma unroll
      for (int r = 0; r < 4; r++) {
        int row = qr + mt * 16 + quad * 4 + r;
        float2 v; v.x = m_run[mt * 4 + r]; v.y = l_run[mt * 4 + r];
        ml[((long)(p0 + sp) * NH + h) * S_LEN + row] = v;
      }
  }
}

// ---------------------------------------------------------------------------
// Combine: out = sum_p w_p O_p (stream1: p0..3, stream2: p4..5), per f16x8 chunk
__global__ void k_combine(const f16* __restrict__ O0, const f16* __restrict__ O1,
                          const f16* __restrict__ O2, const f16* __restrict__ O3,
                          const f16* __restrict__ O4, const f16* __restrict__ O5,
                          const float2* __restrict__ ml, f16* __restrict__ out, int nchunk) {
  int i = blockIdx.x * 256 + threadIdx.x;
  if (i >= nchunk) return;
  int s = i / 384, d8 = i - s * 384, h = d8 >> 4;
  long base = (long)h * S_LEN + s;
  float2 a0 = ml[0 * NH * S_LEN + base];
  float2 a1 = ml[1L * NH * S_LEN + base];
  float2 a2 = ml[2L * NH * S_LEN + base];
  float2 a3 = ml[3L * NH * S_LEN + base];
  float2 a4 = ml[4L * NH * S_LEN + base];
  float2 a5 = ml[5L * NH * S_LEN + base];
  float M1 = fmaxf(fmaxf(a0.x, a1.x), fmaxf(a2.x, a3.x));
  float e0 = __expf(a0.x - M1), e1 = __expf(a1.x - M1), e2 = __expf(a2.x - M1), e3 = __expf(a3.x - M1);
  float L1 = a0.y * e0 + a1.y * e1 + a2.y * e2 + a3.y * e3;
  float w0 = e0 / L1, w1 = e1 / L1, w2 = e2 / L1, w3 = e3 / L1;
  float M2 = fmaxf(a4.x, a5.x);
  float e4 = __expf(a4.x - M2), e5 = __expf(a5.x - M2);
  float L2 = a4.y * e4 + a5.y * e5;
  float w4 = e4 / L2, w5 = e5 / L2;
  f16x8 v0 = ((const f16x8*)O0)[i];
  f16x8 v1 = ((const f16x8*)O1)[i];
  f16x8 v2 = ((const f16x8*)O2)[i];
  f16x8 v3 = ((const f16x8*)O3)[i];
  f16x8 v4 = ((const f16x8*)O4)[i];
  f16x8 v5 = ((const f16x8*)O5)[i];
  f16x8 r;
#pragma unroll
  for (int j = 0; j < 8; j++) {
    float acc = w0 * (float)v0[j] + w1 * (float)v1[j] + w2 * (float)v2[j] + w3 * (float)v3[j]
              + w4 * (float)v4[j] + w5 * (float)v5[j];
    r[j] = (f16)acc;
  }
  ((f16x8*)out)[i] = r;
}

// ---------------------------------------------------------------------------
extern "C" void kernel_launch(void* const* d_in, const int* in_sizes, int n_in,
                              void* d_out, int out_size, void* d_ws, size_t ws_size,
                              hipStream_t stream) {
  const float* hs   = (const float*)d_in[0];
  const float* ip   = (const float*)d_in[1];
  const float* snp  = (const float*)d_in[2];
  const float* csp  = (const float*)d_in[3];
  const float* Wq   = (const float*)d_in[4];
  const float* bq   = (const float*)d_in[5];
  const float* Wk   = (const float*)d_in[6];
  const float* bk   = (const float*)d_in[7];
  const float* Wv   = (const float*)d_in[8];
  const float* bv   = (const float*)d_in[9];
  const float* Wo   = (const float*)d_in[10];
  const float* bo   = (const float*)d_in[11];
  const float* Wkip = (const float*)d_in[12];
  const float* bkip = (const float*)d_in[13];
  const float* Wvip = (const float*)d_in[14];
  const float* bvip = (const float*)d_in[15];
  const float* qs   = (const float*)d_in[16];
  const float* ks   = (const float*)d_in[17];
  float* out = (float*)d_out;

  // sizes (f16 elements)
  const long n1   = 6291456;   // 2048*3072
  const long nW   = 9437184;   // 3072*3072
  const long nip  = 589824;    // 512*1152
  const long nWip = 3538944;   // 3072*1152
  const long nk2  = 1572864;   // 512*3072

  // static layout with lifetime-checked reuse (total 181.3 MB < 191.5 proven)
  const long o_hs   = 0;                       // dead after QKV gemm -> Kps
  const long o_Wq   = 6291456;                 // Wq/Wk/Wv dead after gemm -> Opart0..3
  const long o_Wk   = 15728640;
  const long o_Wv   = 25165824;
  const long o_Wo   = 34603008;                // live till end
  const long o_ip   = 44040192;                // dead after gemm2
  const long o_Wkip = 44630016;                // dead after gemm2 -> Opart4 spans Wkip+Wvip
  const long o_Wvip = 48168960;
  const long o_q    = 51707904;                // dead after rope+rms -> Opart5
  const long o_k    = 57999360;                // dead after krope_pack -> Vps
  const long o_v    = 64290816;                // dead after vpack -> attn
  const long o_kip  = 70582272;                // dead after rmsnorm -> Kpip
  const long o_vip  = 72155136;                // dead after vpack-ip
  const long o_qrot = 73728000;
  const long o_qnorm= 80019456;
  const long o_kipn = 86310912;
  const long o_Vpip = 87883776;
  const long o_ml   = 89456640;                // float2[6*24*2048]
  const long o_Kps  = o_hs;
  const long o_Op0  = o_Wq;                    // p0..p3 stride n1
  const long o_Op4  = o_Wkip;
  const long o_Op5  = o_q;
  const long o_Vps  = o_k;
  const long o_Kpip = o_kip;
  const long o_attn = o_v;

  f16* WS = (f16*)d_ws;
  auto P = [&](long off) { return WS + off; };
  float2* mlp = (float2*)(WS + o_ml);

  // 1) casts
  k_cvt<<<dim3(n1 / 1024),   256, 0, stream>>>(hs,   P(o_hs),   n1 / 4);
  k_cvt<<<dim3(nip / 1024),  256, 0, stream>>>(ip,   P(o_ip),   nip / 4);
  k_cvt<<<dim3(nW / 1024),   256, 0, stream>>>(Wq,   P(o_Wq),   nW / 4);
  k_cvt<<<dim3(nW / 1024),   256, 0, stream>>>(Wk,   P(o_Wk),   nW / 4);
  k_cvt<<<dim3(nW / 1024),   256, 0, stream>>>(Wv,   P(o_Wv),   nW / 4);
  k_cvt<<<dim3(nW / 1024),   256, 0, stream>>>(Wo,   P(o_Wo),   nW / 4);
  k_cvt<<<dim3(nWip / 1024), 256, 0, stream>>>(Wkip, P(o_Wkip), nWip / 4);
  k_cvt<<<dim3(nWip / 1024), 256, 0, stream>>>(Wvip, P(o_Wvip), nWip / 4);

  // 2) projections
  k_gemm_nt<<<dim3(24, 16, 3), 256, 0, stream>>>(P(o_hs),
      P(o_Wq), P(o_Wk), P(o_Wv), bq, bk, bv,
      P(o_q), P(o_k), P(o_v), 2048, 3072, 3072, 0);
  k_gemm_nt<<<dim3(24, 4, 2), 256, 0, stream>>>(P(o_ip),
      P(o_Wkip), P(o_Wvip), P(o_Wvip), bkip, bvip, bvip,
      P(o_kip), P(o_vip), P(o_vip), 512, 3072, 1152, 0);

  // 3) prep: rope(Q), rmsnorm(Q), rope+pack(K), rmsnorm+pack(Kip), pack(V, Vip)
  k_rope<<<dim3(n1 / 256), 256, 0, stream>>>(P(o_q), snp, csp, P(o_qrot), (int)n1);
  k_rmsnorm<<<dim3(49152 / 4), 256, 0, stream>>>(P(o_q),   qs, P(o_qnorm), 49152);
  k_krope_pack<<<dim3(786432 / 256), 256, 0, stream>>>(P(o_k), snp, csp, P(o_Kps), 2048, 786432);
  k_rmsnorm<<<dim3(12288 / 4), 256, 0, stream>>>(P(o_kip), ks, P(o_kipn), 12288);
  k_kpack<<<dim3(196608 / 256), 256, 0, stream>>>(P(o_kipn), P(o_Kpip), 512, 196608);
  k_vpack<<<dim3(32, 24), 256, 0, stream>>>(P(o_v),   P(o_Vps),  2048);
  k_vpack<<<dim3(8, 24),  256, 0, stream>>>(P(o_vip), P(o_Vpip), 512);

  // 4) flash with split-T (self: 4 splits of 512; ip: 2 splits of 256)
  k_flash2<<<dim3(16, 24, 4), 256, 0, stream>>>(P(o_qrot), P(o_Kps), P(o_Vps),
      P(o_Op0), n1, mlp, 0, 2048, 512);
  k_flash2<<<dim3(16, 24, 2), 256, 0, stream>>>(P(o_qnorm), P(o_Kpip), P(o_Vpip),
      P(o_Op4), o_Op5 - o_Op4, mlp, 4, 512, 256);

  // 5) combine partials -> attn (f16)
  k_combine<<<dim3(786432 / 256), 256, 0, stream>>>(
      P(o_Op0), P(o_Op0 + n1), P(o_Op0 + 2 * n1), P(o_Op0 + 3 * n1),
      P(o_Op4), P(o_Op5), mlp, P(o_attn), 786432);

  // 6) output projection -> fp32 d_out
  k_gemm_nt<<<dim3(24, 16, 1), 256, 0, stream>>>(P(o_attn),
      P(o_Wo), P(o_Wo), P(o_Wo), bo, bo, bo,
      out, out, out, 2048, 3072, 3072, 1);
}

// Round 3
// 732.601 us; speedup vs baseline: 1.2696x; 1.0333x over previous
//
#include <hip/hip_runtime.h>
#include <stdint.h>

// Problem constants
#define S_LEN 2048
#define NH    24
#define HD    128
#define HID   3072    // NH*HD
#define IPS   512
#define IPD   1152

using f16   = __fp16;
using f16x4 = __fp16 __attribute__((ext_vector_type(4)));
using f16x8 = __fp16 __attribute__((ext_vector_type(8)));
using f32x4 = float  __attribute__((ext_vector_type(4)));

// ---------------------------------------------------------------------------
// async global->LDS, 16B per lane. LDS dest is wave-uniform base + lane*16.
__device__ __forceinline__ void glds16(const f16* g, f16* l) {
  __builtin_amdgcn_global_load_lds((const __attribute__((address_space(1))) void*)g,
                                   (__attribute__((address_space(3))) void*)l,
                                   16, 0, 0);
}

// ---------------------------------------------------------------------------
// one cast kernel for all 8 fp32->fp16 conversions (saves 7 launches)
struct CastArgs { const float* src[8]; f16* dst[8]; long n4[8]; };

__global__ void k_cvt_all(CastArgs a, long total4) {
  long i = blockIdx.x * 256L + threadIdx.x;
  if (i >= total4) return;
  long r = i; int s = 0;
  while (r >= a.n4[s]) { r -= a.n4[s]; s++; }
  float4 v = ((const float4*)a.src[s])[r];
  f16x4 o;
  o.x = (f16)v.x; o.y = (f16)v.y; o.z = (f16)v.z; o.w = (f16)v.w;
  ((f16x4*)a.dst[s])[r] = o;
}

// ---------------------------------------------------------------------------
// NT GEMM: C[M,N] = A[M,K] @ B[N,K]^T + bias. 128x128 tile, BK=32, 4 waves.
// LDS bank-conflict fix: XOR-swizzled chunk layout. Staging lane reads global
// chunk (c ^ (row>>1)&3) so LDS slot (row,c) holds global chunk c^swz(row);
// fragment reads use chunk quad ^ ((l16>>1)&3) -> 2-way bank aliasing (free).
__global__ __launch_bounds__(256) void k_gemm_nt(
    const f16* __restrict__ A,
    const f16* __restrict__ B0, const f16* __restrict__ B1, const f16* __restrict__ B2,
    const float* __restrict__ bias0, const float* __restrict__ bias1, const float* __restrict__ bias2,
    void* __restrict__ C0, void* __restrict__ C1, void* __restrict__ C2,
    int M, int N, int K, int out_f32)
{
  const int z = blockIdx.z;
  const f16*   B    = (z == 0) ? B0 : (z == 1) ? B1 : B2;
  const float* bias = (z == 0) ? bias0 : (z == 1) ? bias1 : bias2;
  void*        Cv   = (z == 0) ? C0 : (z == 1) ? C1 : C2;

  __shared__ f16 As[128 * 32];
  __shared__ f16 Bs[128 * 32];

  const int tid  = threadIdx.x;
  const int w    = tid >> 6, l = tid & 63;
  const int quad = l >> 4,  l16 = l & 15;
  const int bm = blockIdx.y * 128, bn = blockIdx.x * 128;
  const int wm = (w >> 1) * 64,    wn = (w & 1) * 64;

  f32x4 acc[4][4] = {};

  const int r0 = w * 32;
  const int swz_st = (l >> 3) & 3;                 // (row>>1)&3, row = l>>2
  const int gchunk = ((l & 3) ^ swz_st) * 8;
  const f16* Ag = A + (bm + r0 + (l >> 2)) * K + gchunk;
  const f16* Bg = B + (bn + r0 + (l >> 2)) * K + gchunk;
  f16* lA0 = &As[r0 * 32];
  f16* lA1 = &As[(r0 + 16) * 32];
  f16* lB0 = &Bs[r0 * 32];
  f16* lB1 = &Bs[(r0 + 16) * 32];
  const int kstride16 = 16 * K;
  const int swz_rd = ((l16 >> 1) & 3);             // read-side swizzle

  for (int k0 = 0; k0 < K; k0 += 32) {
    glds16(Ag + k0,             lA0);
    glds16(Ag + kstride16 + k0, lA1);
    glds16(Bg + k0,             lB0);
    glds16(Bg + kstride16 + k0, lB1);
    __syncthreads();

    f16x8 af[4], bf[4];
#pragma unroll
    for (int i = 0; i < 4; i++)
      af[i] = *(const f16x8*)&As[(wm + i * 16 + l16) * 32 + (quad ^ swz_rd) * 8];
#pragma unroll
    for (int j = 0; j < 4; j++)
      bf[j] = *(const f16x8*)&Bs[(wn + j * 16 + l16) * 32 + (quad ^ swz_rd) * 8];
#pragma unroll
    for (int i = 0; i < 4; i++)
#pragma unroll
      for (int j = 0; j < 4; j++)
        acc[i][j] = __builtin_amdgcn_mfma_f32_16x16x32_f16(af[i], bf[j], acc[i][j], 0, 0, 0);
    __syncthreads();
  }

  float bv[4];
#pragma unroll
  for (int j = 0; j < 4; j++) bv[j] = bias[bn + wn + j * 16 + l16];

#pragma unroll
  for (int i = 0; i < 4; i++) {
    const int row0 = bm + wm + i * 16 + quad * 4;
#pragma unroll
    for (int j = 0; j < 4; j++) {
      const int col = bn + wn + j * 16 + l16;
#pragma unroll
      for (int r = 0; r < 4; r++) {
        float v = acc[i][j][r] + bv[j];
        if (out_f32) ((float*)Cv)[(row0 + r) * N + col] = v;
        else         ((f16*)Cv)[(row0 + r) * N + col] = (f16)v;
      }
    }
  }
}

// ---------------------------------------------------------------------------
// Fused Q prep: one pass over q -> qrot (RoPE) and qnorm (RMSNorm*D^-0.5).
// One wave per 128-elem head-row, 2 elems/lane. RoPE partner via shfl_xor 16.
__global__ void k_qprep(const f16* __restrict__ x, const float* __restrict__ snp,
                        const float* __restrict__ csp, const float* __restrict__ scale,
                        f16* __restrict__ qrot, f16* __restrict__ qnorm, int rows) {
  int gw = (blockIdx.x * 256 + threadIdx.x) >> 6;
  int l  = threadIdx.x & 63;
  if (gw >= rows) return;
  long base = (long)gw * HD;
  int s = gw / NH;
  int d = 2 * l;
  float a = (float)x[base + d];
  float b = (float)x[base + d + 1];

  // rmsnorm
  float ss = a * a + b * b;
#pragma unroll
  for (int off = 32; off >= 1; off >>= 1) ss += __shfl_xor(ss, off, 64);
  float rms = sqrtf(ss * (1.0f / HD));
  float inv = 0.08838834764831845f / (rms + 1e-6f);
  qnorm[base + d]     = (f16)(a * scale[d] * inv);
  qnorm[base + d + 1] = (f16)(b * scale[d + 1] * inv);

  // rope
  float pa = __shfl_xor(a, 16, 64);
  float pb = __shfl_xor(b, 16, 64);
  float ra, rb;
  if (d < 64) {
    float sgn = (d < 32) ? -1.0f : 1.0f;
    ra = a * csp[s * 64 + d]     + sgn * pa * snp[s * 64 + d];
    rb = b * csp[s * 64 + d + 1] + sgn * pb * snp[s * 64 + d + 1];
  } else {
    ra = a; rb = b;
  }
  qrot[base + d]     = (f16)ra;
  qrot[base + d + 1] = (f16)rb;
}

// ---------------------------------------------------------------------------
// K-self: RoPE + pack into QK B-fragment order (one pass).
__global__ void k_krope_pack(const f16* __restrict__ src, const float* __restrict__ snp,
                             const float* __restrict__ csp, f16* __restrict__ dst,
                             int T, int nchunk) {
  int i = blockIdx.x * 256 + threadIdx.x;
  if (i >= nchunk) return;
  int d8 = i % 384;
  int t  = i / 384;
  int h  = d8 >> 4;
  int d  = (d8 & 15) * 8;
  f16x8 x = *(const f16x8*)(src + (long)i * 8);
  f16x8 o;
  if (d < 64) {
    f16x8 p = (d < 32) ? *(const f16x8*)(src + (long)i * 8 + 32)
                       : *(const f16x8*)(src + (long)i * 8 - 32);
    float sgn = (d < 32) ? -1.0f : 1.0f;
#pragma unroll
    for (int j = 0; j < 8; j++) {
      float cs = csp[t * 64 + d + j], sn = snp[t * 64 + d + j];
      o[j] = (f16)((float)x[j] * cs + sgn * (float)p[j] * sn);
    }
  } else {
    o = x;
  }
  long off = ((((long)h * (T >> 4) + (t >> 4)) * 4 + (d >> 5)) * 64 + ((d >> 3) & 3) * 16 + (t & 15)) * 8;
  *(f16x8*)(dst + off) = o;
}

// ---------------------------------------------------------------------------
// K-ip: RMSNorm*D^-0.5 + pack into QK B-fragment order (one pass).
// Wave = 4 rows x 16 lanes, 8 elems/lane.
__global__ void k_rms_pack(const f16* __restrict__ x, const float* __restrict__ scale,
                           f16* __restrict__ dst, int T, int rows) {
  int gw  = (blockIdx.x * 256 + threadIdx.x) >> 6;
  int l   = threadIdx.x & 63;
  int sub = l >> 4, l16 = l & 15;
  int row = gw * 4 + sub;
  if (row >= rows) return;
  int t = row / NH, h = row - t * NH;
  int d = l16 * 8;
  f16x8 v = *(const f16x8*)(x + (long)row * HD + d);
  float ss = 0.f;
#pragma unroll
  for (int j = 0; j < 8; j++) { float f = (float)v[j]; ss += f * f; }
  ss += __shfl_xor(ss, 1, 64);
  ss += __shfl_xor(ss, 2, 64);
  ss += __shfl_xor(ss, 4, 64);
  ss += __shfl_xor(ss, 8, 64);
  float rms = sqrtf(ss * (1.0f / HD));
  float inv = 0.08838834764831845f / (rms + 1e-6f);
  f16x8 o;
#pragma unroll
  for (int j = 0; j < 8; j++) o[j] = (f16)((float)v[j] * scale[d + j] * inv);
  long off = ((((long)h * (T >> 4) + (t >> 4)) * 4 + (d >> 5)) * 64 + ((d >> 3) & 3) * 16 + (t & 15)) * 8;
  *(f16x8*)(dst + off) = o;
}

// ---------------------------------------------------------------------------
// Pack V [T][HID] -> PV B-fragment order (transposed: frag j indexes t).
__global__ __launch_bounds__(256) void k_vpack(const f16* __restrict__ v, f16* __restrict__ dst, int T) {
  __shared__ f16 Ts[128 * 72];   // [d][t], ld=72
  int h = blockIdx.y, tb = blockIdx.x, t0 = tb * 64;
  int tid = threadIdx.x;
  int r = tid >> 2, c4 = tid & 3;
#pragma unroll
  for (int cc = 0; cc < 4; cc++) {
    int ch = c4 * 4 + cc;
    f16x8 x = *(const f16x8*)(v + (long)(t0 + r) * HID + h * HD + ch * 8);
#pragma unroll
    for (int j = 0; j < 8; j++)
      Ts[(ch * 8 + j) * 72 + r] = x[j];
  }
  __syncthreads();
  int l16 = tid & 15, jd = (tid >> 4) & 7, ks = tid >> 7;
#pragma unroll
  for (int quad = 0; quad < 4; quad++) {
    f16x8 x = *(const f16x8*)&Ts[(jd * 16 + l16) * 72 + ks * 32 + quad * 8];
    long off = ((((long)h * (T >> 6) + tb) * 2 + ks) * 8 + jd) * 512 + (quad * 16 + l16) * 8;
    *(f16x8*)(dst + off) = x;
  }
}

// ---------------------------------------------------------------------------
// Flash attention with split-T. Block = (128 q-rows, head, T-split).
// Writes UNNORMALIZED max-shifted partial O (f16) + per-row (m,l) float2.
__global__ __launch_bounds__(256) void k_flash2(
    const f16* __restrict__ Q, const f16* __restrict__ Kp, const f16* __restrict__ Vp,
    f16* __restrict__ Opart, long part_stride, float2* __restrict__ ml, int p0,
    int T, int Tc)
{
  __shared__ f16 Ps[4][32 * 72];   // per-wave P tile, no barrier needed

  const int h    = blockIdx.y;
  const int sp   = blockIdx.z;
  const int tid  = threadIdx.x, w = tid >> 6, l = tid & 63;
  const int quad = l >> 4, l16 = l & 15;
  const int qr   = blockIdx.x * 128 + w * 32;
  const int Tt16 = T >> 4, Tt64 = T >> 6;

  f16x8 qf[2][4];
#pragma unroll
  for (int mt = 0; mt < 2; mt++)
#pragma unroll
    for (int kq = 0; kq < 4; kq++)
      qf[mt][kq] = *(const f16x8*)(Q + (long)(qr + mt * 16 + l16) * HID + h * HD + kq * 32 + quad * 8);

  f32x4 o[2][8] = {};
  float m_run[8], l_run[8];
#pragma unroll
  for (int i = 0; i < 8; i++) { m_run[i] = -1e30f; l_run[i] = 0.f; }

  f16* myP = &Ps[w][0];
  const int t_begin = sp * Tc, t_end = t_begin + Tc;

  for (int t0 = t_begin; t0 < t_end; t0 += 64) {
    f32x4 s[2][4] = {};
#pragma unroll
    for (int kq = 0; kq < 4; kq++) {
      f16x8 kf[4];
#pragma unroll
      for (int jn = 0; jn < 4; jn++)
        kf[jn] = *(const f16x8*)(Kp + (((long)(h * Tt16 + (t0 >> 4) + jn) * 4 + kq) * 64 + l) * 8);
#pragma unroll
      for (int mt = 0; mt < 2; mt++)
#pragma unroll
        for (int jn = 0; jn < 4; jn++)
          s[mt][jn] = __builtin_amdgcn_mfma_f32_16x16x32_f16(qf[mt][kq], kf[jn], s[mt][jn], 0, 0, 0);
    }

#pragma unroll
    for (int mt = 0; mt < 2; mt++) {
#pragma unroll
      for (int r = 0; r < 4; r++) {
        float mx = fmaxf(fmaxf(s[mt][0][r], s[mt][1][r]), fmaxf(s[mt][2][r], s[mt][3][r]));
        mx = fmaxf(mx, __shfl_xor(mx, 1, 64));
        mx = fmaxf(mx, __shfl_xor(mx, 2, 64));
        mx = fmaxf(mx, __shfl_xor(mx, 4, 64));
        mx = fmaxf(mx, __shfl_xor(mx, 8, 64));
        const int ri = mt * 4 + r;
        float mn = fmaxf(m_run[ri], mx);
        float al = __expf(m_run[ri] - mn);
        m_run[ri] = mn;
        float p0v = __expf(s[mt][0][r] - mn);
        float p1v = __expf(s[mt][1][r] - mn);
        float p2v = __expf(s[mt][2][r] - mn);
        float p3v = __expf(s[mt][3][r] - mn);
        s[mt][0][r] = p0v; s[mt][1][r] = p1v; s[mt][2][r] = p2v; s[mt][3][r] = p3v;
        l_run[ri] = l_run[ri] * al + (p0v + p1v + p2v + p3v);
#pragma unroll
        for (int jd = 0; jd < 8; jd++) o[mt][jd][r] *= al;
      }
    }

#pragma unroll
    for (int mt = 0; mt < 2; mt++)
#pragma unroll
      for (int jn = 0; jn < 4; jn++)
#pragma unroll
        for (int r = 0; r < 4; r++)
          myP[(mt * 16 + quad * 4 + r) * 72 + jn * 16 + l16] = (f16)s[mt][jn][r];

#pragma unroll
    for (int ks = 0; ks < 2; ks++) {
      f16x8 pf[2];
#pragma unroll
      for (int mt = 0; mt < 2; mt++)
        pf[mt] = *(const f16x8*)&myP[(mt * 16 + l16) * 72 + ks * 32 + quad * 8];
      f16x8 vf[8];
#pragma unroll
      for (int jd = 0; jd < 8; jd++)
        vf[jd] = *(const f16x8*)(Vp + ((((long)(h * Tt64 + (t0 >> 6)) * 2 + ks) * 8 + jd) * 64 + l) * 8);
#pragma unroll
      for (int jd = 0; jd < 8; jd++)
#pragma unroll
        for (int mt = 0; mt < 2; mt++)
          o[mt][jd] = __builtin_amdgcn_mfma_f32_16x16x32_f16(pf[mt], vf[jd], o[mt][jd], 0, 0, 0);
    }
  }

#pragma unroll
  for (int i = 0; i < 8; i++) {
    float v = l_run[i];
    v += __shfl_xor(v, 1, 64);
    v += __shfl_xor(v, 2, 64);
    v += __shfl_xor(v, 4, 64);
    v += __shfl_xor(v, 8, 64);
    l_run[i] = v;
  }

  f16* Od = Opart + (long)sp * part_stride;
#pragma unroll
  for (int mt = 0; mt < 2; mt++)
#pragma unroll
    for (int jd = 0; jd < 8; jd++)
#pragma unroll
      for (int r = 0; r < 4; r++) {
        int row = qr + mt * 16 + quad * 4 + r;
        int col = h * HD + jd * 16 + l16;
        Od[(long)row * HID + col] = (f16)o[mt][jd][r];
      }
  if (l16 == 0) {
#pragma unroll
    for (int mt = 0; mt < 2; mt++)
#pragma unroll
      for (int r = 0; r < 4; r++) {
        int row = qr + mt * 16 + quad * 4 + r;
        float2 v; v.x = m_run[mt * 4 + r]; v.y = l_run[mt * 4 + r];
        ml[((long)(p0 + sp) * NH + h) * S_LEN + row] = v;
      }
  }
}

// ---------------------------------------------------------------------------
// Combine: out = sum_p w_p O_p (stream1: p0..3, stream2: p4..5), per f16x8 chunk
__global__ void k_combine(const f16* __restrict__ O0, const f16* __restrict__ O1,
                          const f16* __restrict__ O2, const f16* __restrict__ O3,
                          const f16* __restrict__ O4, const f16* __restrict__ O5,
                          const float2* __restrict__ ml, f16* __restrict__ out, int nchunk) {
  int i = blockIdx.x * 256 + threadIdx.x;
  if (i >= nchunk) return;
  int s = i / 384, d8 = i - s * 384, h = d8 >> 4;
  long base = (long)h * S_LEN + s;
  float2 a0 = ml[0 * NH * S_LEN + base];
  float2 a1 = ml[1L * NH * S_LEN + base];
  float2 a2 = ml[2L * NH * S_LEN + base];
  float2 a3 = ml[3L * NH * S_LEN + base];
  float2 a4 = ml[4L * NH * S_LEN + base];
  float2 a5 = ml[5L * NH * S_LEN + base];
  float M1 = fmaxf(fmaxf(a0.x, a1.x), fmaxf(a2.x, a3.x));
  float e0 = __expf(a0.x - M1), e1 = __expf(a1.x - M1), e2 = __expf(a2.x - M1), e3 = __expf(a3.x - M1);
  float L1 = a0.y * e0 + a1.y * e1 + a2.y * e2 + a3.y * e3;
  float w0 = e0 / L1, w1 = e1 / L1, w2 = e2 / L1, w3 = e3 / L1;
  float M2 = fmaxf(a4.x, a5.x);
  float e4 = __expf(a4.x - M2), e5 = __expf(a5.x - M2);
  float L2 = a4.y * e4 + a5.y * e5;
  float w4 = e4 / L2, w5 = e5 / L2;
  f16x8 v0 = ((const f16x8*)O0)[i];
  f16x8 v1 = ((const f16x8*)O1)[i];
  f16x8 v2 = ((const f16x8*)O2)[i];
  f16x8 v3 = ((const f16x8*)O3)[i];
  f16x8 v4 = ((const f16x8*)O4)[i];
  f16x8 v5 = ((const f16x8*)O5)[i];
  f16x8 r;
#pragma unroll
  for (int j = 0; j < 8; j++) {
    float acc = w0 * (float)v0[j] + w1 * (float)v1[j] + w2 * (float)v2[j] + w3 * (float)v3[j]
              + w4 * (float)v4[j] + w5 * (float)v5[j];
    r[j] = (f16)acc;
  }
  ((f16x8*)out)[i] = r;
}

// ---------------------------------------------------------------------------
extern "C" void kernel_launch(void* const* d_in, const int* in_sizes, int n_in,
                              void* d_out, int out_size, void* d_ws, size_t ws_size,
                              hipStream_t stream) {
  const float* hs   = (const float*)d_in[0];
  const float* ip   = (const float*)d_in[1];
  const float* snp  = (const float*)d_in[2];
  const float* csp  = (const float*)d_in[3];
  const float* Wq   = (const float*)d_in[4];
  const float* bq   = (const float*)d_in[5];
  const float* Wk   = (const float*)d_in[6];
  const float* bk   = (const float*)d_in[7];
  const float* Wv   = (const float*)d_in[8];
  const float* bv   = (const float*)d_in[9];
  const float* Wo   = (const float*)d_in[10];
  const float* bo   = (const float*)d_in[11];
  const float* Wkip = (const float*)d_in[12];
  const float* bkip = (const float*)d_in[13];
  const float* Wvip = (const float*)d_in[14];
  const float* bvip = (const float*)d_in[15];
  const float* qs   = (const float*)d_in[16];
  const float* ks   = (const float*)d_in[17];
  float* out = (float*)d_out;

  // sizes (f16 elements)
  const long n1   = 6291456;   // 2048*3072
  const long nW   = 9437184;   // 3072*3072
  const long nip  = 589824;    // 512*1152
  const long nWip = 3538944;   // 3072*1152

  // static layout with lifetime-checked reuse
  const long o_hs   = 0;
  const long o_Wq   = 6291456;
  const long o_Wk   = 15728640;
  const long o_Wv   = 25165824;
  const long o_Wo   = 34603008;
  const long o_ip   = 44040192;
  const long o_Wkip = 44630016;
  const long o_Wvip = 48168960;
  const long o_q    = 51707904;
  const long o_k    = 57999360;
  const long o_v    = 64290816;
  const long o_kip  = 70582272;
  const long o_vip  = 72155136;
  const long o_qrot = 73728000;
  const long o_qnorm= 80019456;
  const long o_kipn = 86310912;   // unused now (rms fused into pack), kept as spare
  const long o_Vpip = 87883776;
  const long o_ml   = 89456640;   // float2[6*24*2048]
  const long o_Kps  = o_hs;
  const long o_Op0  = o_Wq;       // p0..p3 stride n1
  const long o_Op4  = o_Wkip;
  const long o_Op5  = o_q;
  const long o_Vps  = o_k;
  const long o_Kpip = o_kip;
  const long o_attn = o_v;

  f16* WS = (f16*)d_ws;
  auto P = [&](long off) { return WS + off; };
  float2* mlp = (float2*)(WS + o_ml);

  // 1) all casts in one launch
  CastArgs ca;
  ca.src[0] = hs;   ca.dst[0] = P(o_hs);   ca.n4[0] = n1 / 4;
  ca.src[1] = ip;   ca.dst[1] = P(o_ip);   ca.n4[1] = nip / 4;
  ca.src[2] = Wq;   ca.dst[2] = P(o_Wq);   ca.n4[2] = nW / 4;
  ca.src[3] = Wk;   ca.dst[3] = P(o_Wk);   ca.n4[3] = nW / 4;
  ca.src[4] = Wv;   ca.dst[4] = P(o_Wv);   ca.n4[4] = nW / 4;
  ca.src[5] = Wo;   ca.dst[5] = P(o_Wo);   ca.n4[5] = nW / 4;
  ca.src[6] = Wkip; ca.dst[6] = P(o_Wkip); ca.n4[6] = nWip / 4;
  ca.src[7] = Wvip; ca.dst[7] = P(o_Wvip); ca.n4[7] = nWip / 4;
  const long total4 = (n1 + nip + 4 * nW + 2 * nWip) / 4;   // 12926976
  k_cvt_all<<<dim3((total4 + 255) / 256), 256, 0, stream>>>(ca, total4);

  // 2) projections
  k_gemm_nt<<<dim3(24, 16, 3), 256, 0, stream>>>(P(o_hs),
      P(o_Wq), P(o_Wk), P(o_Wv), bq, bk, bv,
      P(o_q), P(o_k), P(o_v), 2048, 3072, 3072, 0);
  k_gemm_nt<<<dim3(24, 4, 2), 256, 0, stream>>>(P(o_ip),
      P(o_Wkip), P(o_Wvip), P(o_Wvip), bkip, bvip, bvip,
      P(o_kip), P(o_vip), P(o_vip), 512, 3072, 1152, 0);

  // 3) prep (fused): qprep, krope_pack, rms_pack(ip), vpacks
  k_qprep<<<dim3(49152 / 4), 256, 0, stream>>>(P(o_q), snp, csp, qs, P(o_qrot), P(o_qnorm), 49152);
  k_krope_pack<<<dim3(786432 / 256), 256, 0, stream>>>(P(o_k), snp, csp, P(o_Kps), 2048, 786432);
  k_rms_pack<<<dim3(12288 / 16), 256, 0, stream>>>(P(o_kip), ks, P(o_Kpip), 512, 12288);
  k_vpack<<<dim3(32, 24), 256, 0, stream>>>(P(o_v),   P(o_Vps),  2048);
  k_vpack<<<dim3(8, 24),  256, 0, stream>>>(P(o_vip), P(o_Vpip), 512);

  // 4) flash with split-T (self: 4 splits of 512; ip: 2 splits of 256)
  k_flash2<<<dim3(16, 24, 4), 256, 0, stream>>>(P(o_qrot), P(o_Kps), P(o_Vps),
      P(o_Op0), n1, mlp, 0, 2048, 512);
  k_flash2<<<dim3(16, 24, 2), 256, 0, stream>>>(P(o_qnorm), P(o_Kpip), P(o_Vpip),
      P(o_Op4), o_Op5 - o_Op4, mlp, 4, 512, 256);

  // 5) combine partials -> attn (f16)
  k_combine<<<dim3(786432 / 256), 256, 0, stream>>>(
      P(o_Op0), P(o_Op0 + n1), P(o_Op0 + 2 * n1), P(o_Op0 + 3 * n1),
      P(o_Op4), P(o_Op5), mlp, P(o_attn), 786432);

  // 6) output projection -> fp32 d_out
  k_gemm_nt<<<dim3(24, 16, 1), 256, 0, stream>>>(P(o_attn),
      P(o_Wo), P(o_Wo), P(o_Wo), bo, bo, bo,
      out, out, out, 2048, 3072, 3072, 1);
}

// Round 4
// 694.921 us; speedup vs baseline: 1.3385x; 1.0542x over previous
//
#include <hip/hip_runtime.h>
#include <stdint.h>

// Problem constants
#define S_LEN 2048
#define NH    24
#define HD    128
#define HID   3072    // NH*HD
#define IPS   512
#define IPD   1152

using f16   = __fp16;
using f16x4 = __fp16 __attribute__((ext_vector_type(4)));
using f16x8 = __fp16 __attribute__((ext_vector_type(8)));
using f32x4 = float  __attribute__((ext_vector_type(4)));
using f32x16 = float __attribute__((ext_vector_type(16)));

// ---------------------------------------------------------------------------
// async global->LDS, 16B per lane. LDS dest is wave-uniform base + lane*16.
__device__ __forceinline__ void glds16(const f16* g, f16* l) {
  __builtin_amdgcn_global_load_lds((const __attribute__((address_space(1))) void*)g,
                                   (__attribute__((address_space(3))) void*)l,
                                   16, 0, 0);
}

// ---------------------------------------------------------------------------
// one cast kernel for all 8 fp32->fp16 conversions
struct CastArgs { const float* src[8]; f16* dst[8]; long n4[8]; };

__global__ void k_cvt_all(CastArgs a, long total4) {
  long i = blockIdx.x * 256L + threadIdx.x;
  if (i >= total4) return;
  long r = i; int s = 0;
  while (r >= a.n4[s]) { r -= a.n4[s]; s++; }
  float4 v = ((const float4*)a.src[s])[r];
  f16x4 o;
  o.x = (f16)v.x; o.y = (f16)v.y; o.z = (f16)v.z; o.w = (f16)v.w;
  ((f16x4*)a.dst[s])[r] = o;
}

// ---------------------------------------------------------------------------
// NT GEMM: C[M,N] = A[M,K] @ B[N,K]^T + bias. 128x128 tile, BK=64, 4 waves,
// 32x32x16 MFMA (2x2 tiles of 32x32 per wave).
// LDS: row-major 128x64 per matrix, XOR-chunk swizzle over 8 positions:
//   slot(row,pos) holds global chunk pos^(row&7); read pos = c^(row&7).
// -> balanced 8 dwords/bank on ds_read_b128 (conflict-free floor), and
//    staging stays lane-contiguous for global_load_lds (16B/lane).
__global__ __launch_bounds__(256) void k_gemm_nt(
    const f16* __restrict__ A,
    const f16* __restrict__ B0, const f16* __restrict__ B1, const f16* __restrict__ B2,
    const float* __restrict__ bias0, const float* __restrict__ bias1, const float* __restrict__ bias2,
    void* __restrict__ C0, void* __restrict__ C1, void* __restrict__ C2,
    int M, int N, int K, int out_f32)
{
  const int z = blockIdx.z;
  const f16*   B    = (z == 0) ? B0 : (z == 1) ? B1 : B2;
  const float* bias = (z == 0) ? bias0 : (z == 1) ? bias1 : bias2;
  void*        Cv   = (z == 0) ? C0 : (z == 1) ? C1 : C2;

  __shared__ f16 As[128 * 64];
  __shared__ f16 Bs[128 * 64];

  const int tid = threadIdx.x;
  const int w   = tid >> 6, l = tid & 63;
  const int l31 = l & 31, hi = l >> 5;
  const int bm = blockIdx.y * 128, bn = blockIdx.x * 128;
  const int wm = (w >> 1) * 64,    wn = (w & 1) * 64;

  f32x16 acc[2][2] = {};

  // staging: wave stages 32 rows of A and B (4 glds16 each, 8 rows/instr)
  const int r0   = w * 32;
  const int srow = l >> 3;                    // row within 8-row group
  const int gch  = (l & 7) ^ (srow & 7);      // swizzled global chunk
  const f16* Ag = A + (long)(bm + r0 + srow) * K + gch * 8;
  const f16* Bg = B + (long)(bn + r0 + srow) * K + gch * 8;
  f16* lA = &As[r0 * 64];
  f16* lB = &Bs[r0 * 64];
  const long rs8 = 8L * K;

  const int swz = l & 7;                      // read-side swizzle key (row&7)

  for (int k0 = 0; k0 < K; k0 += 64) {
#pragma unroll
    for (int g = 0; g < 4; g++) {
      glds16(Ag + g * rs8 + k0, lA + g * 512);
      glds16(Bg + g * rs8 + k0, lB + g * 512);
    }
    __syncthreads();

#pragma unroll
    for (int ks = 0; ks < 4; ks++) {
      const int pos = ((ks * 2 + hi) ^ swz) * 8;
      f16x8 af[2], bf[2];
#pragma unroll
      for (int mi = 0; mi < 2; mi++)
        af[mi] = *(const f16x8*)&As[(wm + mi * 32 + l31) * 64 + pos];
#pragma unroll
      for (int nj = 0; nj < 2; nj++)
        bf[nj] = *(const f16x8*)&Bs[(wn + nj * 32 + l31) * 64 + pos];
#pragma unroll
      for (int mi = 0; mi < 2; mi++)
#pragma unroll
        for (int nj = 0; nj < 2; nj++)
          acc[mi][nj] = __builtin_amdgcn_mfma_f32_32x32x16_f16(af[mi], bf[nj], acc[mi][nj], 0, 0, 0);
    }
    __syncthreads();
  }

  // epilogue: C/D layout col=lane&31, row=(reg&3)+8*(reg>>2)+4*(lane>>5)
#pragma unroll
  for (int mi = 0; mi < 2; mi++)
#pragma unroll
    for (int nj = 0; nj < 2; nj++) {
      const int col = bn + wn + nj * 32 + l31;
      const float bvv = bias[col];
      const int rowb = bm + wm + mi * 32 + 4 * hi;
#pragma unroll
      for (int reg = 0; reg < 16; reg++) {
        const int row = rowb + (reg & 3) + 8 * (reg >> 2);
        float v = acc[mi][nj][reg] + bvv;
        if (out_f32) ((float*)Cv)[(long)row * N + col] = v;
        else         ((f16*)Cv)[(long)row * N + col] = (f16)v;
      }
    }
}

// ---------------------------------------------------------------------------
// Fused Q prep: one pass over q -> qrot (RoPE) and qnorm (RMSNorm*D^-0.5).
__global__ void k_qprep(const f16* __restrict__ x, const float* __restrict__ snp,
                        const float* __restrict__ csp, const float* __restrict__ scale,
                        f16* __restrict__ qrot, f16* __restrict__ qnorm, int rows) {
  int gw = (blockIdx.x * 256 + threadIdx.x) >> 6;
  int l  = threadIdx.x & 63;
  if (gw >= rows) return;
  long base = (long)gw * HD;
  int s = gw / NH;
  int d = 2 * l;
  float a = (float)x[base + d];
  float b = (float)x[base + d + 1];

  float ss = a * a + b * b;
#pragma unroll
  for (int off = 32; off >= 1; off >>= 1) ss += __shfl_xor(ss, off, 64);
  float rms = sqrtf(ss * (1.0f / HD));
  float inv = 0.08838834764831845f / (rms + 1e-6f);
  qnorm[base + d]     = (f16)(a * scale[d] * inv);
  qnorm[base + d + 1] = (f16)(b * scale[d + 1] * inv);

  float pa = __shfl_xor(a, 16, 64);
  float pb = __shfl_xor(b, 16, 64);
  float ra, rb;
  if (d < 64) {
    float sgn = (d < 32) ? -1.0f : 1.0f;
    ra = a * csp[s * 64 + d]     + sgn * pa * snp[s * 64 + d];
    rb = b * csp[s * 64 + d + 1] + sgn * pb * snp[s * 64 + d + 1];
  } else {
    ra = a; rb = b;
  }
  qrot[base + d]     = (f16)ra;
  qrot[base + d + 1] = (f16)rb;
}

// ---------------------------------------------------------------------------
// K-self: RoPE + pack into QK B-fragment order (one pass).
__global__ void k_krope_pack(const f16* __restrict__ src, const float* __restrict__ snp,
                             const float* __restrict__ csp, f16* __restrict__ dst,
                             int T, int nchunk) {
  int i = blockIdx.x * 256 + threadIdx.x;
  if (i >= nchunk) return;
  int d8 = i % 384;
  int t  = i / 384;
  int h  = d8 >> 4;
  int d  = (d8 & 15) * 8;
  f16x8 x = *(const f16x8*)(src + (long)i * 8);
  f16x8 o;
  if (d < 64) {
    f16x8 p = (d < 32) ? *(const f16x8*)(src + (long)i * 8 + 32)
                       : *(const f16x8*)(src + (long)i * 8 - 32);
    float sgn = (d < 32) ? -1.0f : 1.0f;
#pragma unroll
    for (int j = 0; j < 8; j++) {
      float cs = csp[t * 64 + d + j], sn = snp[t * 64 + d + j];
      o[j] = (f16)((float)x[j] * cs + sgn * (float)p[j] * sn);
    }
  } else {
    o = x;
  }
  long off = ((((long)h * (T >> 4) + (t >> 4)) * 4 + (d >> 5)) * 64 + ((d >> 3) & 3) * 16 + (t & 15)) * 8;
  *(f16x8*)(dst + off) = o;
}

// ---------------------------------------------------------------------------
// K-ip: RMSNorm*D^-0.5 + pack into QK B-fragment order (one pass).
__global__ void k_rms_pack(const f16* __restrict__ x, const float* __restrict__ scale,
                           f16* __restrict__ dst, int T, int rows) {
  int gw  = (blockIdx.x * 256 + threadIdx.x) >> 6;
  int l   = threadIdx.x & 63;
  int sub = l >> 4, l16 = l & 15;
  int row = gw * 4 + sub;
  if (row >= rows) return;
  int t = row / NH, h = row - t * NH;
  int d = l16 * 8;
  f16x8 v = *(const f16x8*)(x + (long)row * HD + d);
  float ss = 0.f;
#pragma unroll
  for (int j = 0; j < 8; j++) { float f = (float)v[j]; ss += f * f; }
  ss += __shfl_xor(ss, 1, 64);
  ss += __shfl_xor(ss, 2, 64);
  ss += __shfl_xor(ss, 4, 64);
  ss += __shfl_xor(ss, 8, 64);
  float rms = sqrtf(ss * (1.0f / HD));
  float inv = 0.08838834764831845f / (rms + 1e-6f);
  f16x8 o;
#pragma unroll
  for (int j = 0; j < 8; j++) o[j] = (f16)((float)v[j] * scale[d + j] * inv);
  long off = ((((long)h * (T >> 4) + (t >> 4)) * 4 + (d >> 5)) * 64 + ((d >> 3) & 3) * 16 + (t & 15)) * 8;
  *(f16x8*)(dst + off) = o;
}

// ---------------------------------------------------------------------------
// Pack V [T][HID] -> PV B-fragment order (transposed: frag j indexes t).
__global__ __launch_bounds__(256) void k_vpack(const f16* __restrict__ v, f16* __restrict__ dst, int T) {
  __shared__ f16 Ts[128 * 72];   // [d][t], ld=72
  int h = blockIdx.y, tb = blockIdx.x, t0 = tb * 64;
  int tid = threadIdx.x;
  int r = tid >> 2, c4 = tid & 3;
#pragma unroll
  for (int cc = 0; cc < 4; cc++) {
    int ch = c4 * 4 + cc;
    f16x8 x = *(const f16x8*)(v + (long)(t0 + r) * HID + h * HD + ch * 8);
#pragma unroll
    for (int j = 0; j < 8; j++)
      Ts[(ch * 8 + j) * 72 + r] = x[j];
  }
  __syncthreads();
  int l16 = tid & 15, jd = (tid >> 4) & 7, ks = tid >> 7;
#pragma unroll
  for (int quad = 0; quad < 4; quad++) {
    f16x8 x = *(const f16x8*)&Ts[(jd * 16 + l16) * 72 + ks * 32 + quad * 8];
    long off = ((((long)h * (T >> 6) + tb) * 2 + ks) * 8 + jd) * 512 + (quad * 16 + l16) * 8;
    *(f16x8*)(dst + off) = x;
  }
}

// ---------------------------------------------------------------------------
// Flash attention with split-T. Block = (128 q-rows, head, T-split).
__global__ __launch_bounds__(256) void k_flash2(
    const f16* __restrict__ Q, const f16* __restrict__ Kp, const f16* __restrict__ Vp,
    f16* __restrict__ Opart, long part_stride, float2* __restrict__ ml, int p0,
    int T, int Tc)
{
  __shared__ f16 Ps[4][32 * 72];   // per-wave P tile, no barrier needed

  const int h    = blockIdx.y;
  const int sp   = blockIdx.z;
  const int tid  = threadIdx.x, w = tid >> 6, l = tid & 63;
  const int quad = l >> 4, l16 = l & 15;
  const int qr   = blockIdx.x * 128 + w * 32;
  const int Tt16 = T >> 4, Tt64 = T >> 6;

  f16x8 qf[2][4];
#pragma unroll
  for (int mt = 0; mt < 2; mt++)
#pragma unroll
    for (int kq = 0; kq < 4; kq++)
      qf[mt][kq] = *(const f16x8*)(Q + (long)(qr + mt * 16 + l16) * HID + h * HD + kq * 32 + quad * 8);

  f32x4 o[2][8] = {};
  float m_run[8], l_run[8];
#pragma unroll
  for (int i = 0; i < 8; i++) { m_run[i] = -1e30f; l_run[i] = 0.f; }

  f16* myP = &Ps[w][0];
  const int t_begin = sp * Tc, t_end = t_begin + Tc;

  for (int t0 = t_begin; t0 < t_end; t0 += 64) {
    f32x4 s[2][4] = {};
#pragma unroll
    for (int kq = 0; kq < 4; kq++) {
      f16x8 kf[4];
#pragma unroll
      for (int jn = 0; jn < 4; jn++)
        kf[jn] = *(const f16x8*)(Kp + (((long)(h * Tt16 + (t0 >> 4) + jn) * 4 + kq) * 64 + l) * 8);
#pragma unroll
      for (int mt = 0; mt < 2; mt++)
#pragma unroll
        for (int jn = 0; jn < 4; jn++)
          s[mt][jn] = __builtin_amdgcn_mfma_f32_16x16x32_f16(qf[mt][kq], kf[jn], s[mt][jn], 0, 0, 0);
    }

#pragma unroll
    for (int mt = 0; mt < 2; mt++) {
#pragma unroll
      for (int r = 0; r < 4; r++) {
        float mx = fmaxf(fmaxf(s[mt][0][r], s[mt][1][r]), fmaxf(s[mt][2][r], s[mt][3][r]));
        mx = fmaxf(mx, __shfl_xor(mx, 1, 64));
        mx = fmaxf(mx, __shfl_xor(mx, 2, 64));
        mx = fmaxf(mx, __shfl_xor(mx, 4, 64));
        mx = fmaxf(mx, __shfl_xor(mx, 8, 64));
        const int ri = mt * 4 + r;
        float mn = fmaxf(m_run[ri], mx);
        float al = __expf(m_run[ri] - mn);
        m_run[ri] = mn;
        float p0v = __expf(s[mt][0][r] - mn);
        float p1v = __expf(s[mt][1][r] - mn);
        float p2v = __expf(s[mt][2][r] - mn);
        float p3v = __expf(s[mt][3][r] - mn);
        s[mt][0][r] = p0v; s[mt][1][r] = p1v; s[mt][2][r] = p2v; s[mt][3][r] = p3v;
        l_run[ri] = l_run[ri] * al + (p0v + p1v + p2v + p3v);
#pragma unroll
        for (int jd = 0; jd < 8; jd++) o[mt][jd][r] *= al;
      }
    }

#pragma unroll
    for (int mt = 0; mt < 2; mt++)
#pragma unroll
      for (int jn = 0; jn < 4; jn++)
#pragma unroll
        for (int r = 0; r < 4; r++)
          myP[(mt * 16 + quad * 4 + r) * 72 + jn * 16 + l16] = (f16)s[mt][jn][r];

#pragma unroll
    for (int ks = 0; ks < 2; ks++) {
      f16x8 pf[2];
#pragma unroll
      for (int mt = 0; mt < 2; mt++)
        pf[mt] = *(const f16x8*)&myP[(mt * 16 + l16) * 72 + ks * 32 + quad * 8];
      f16x8 vf[8];
#pragma unroll
      for (int jd = 0; jd < 8; jd++)
        vf[jd] = *(const f16x8*)(Vp + ((((long)(h * Tt64 + (t0 >> 6)) * 2 + ks) * 8 + jd) * 64 + l) * 8);
#pragma unroll
      for (int jd = 0; jd < 8; jd++)
#pragma unroll
        for (int mt = 0; mt < 2; mt++)
          o[mt][jd] = __builtin_amdgcn_mfma_f32_16x16x32_f16(pf[mt], vf[jd], o[mt][jd], 0, 0, 0);
    }
  }

#pragma unroll
  for (int i = 0; i < 8; i++) {
    float v = l_run[i];
    v += __shfl_xor(v, 1, 64);
    v += __shfl_xor(v, 2, 64);
    v += __shfl_xor(v, 4, 64);
    v += __shfl_xor(v, 8, 64);
    l_run[i] = v;
  }

  f16* Od = Opart + (long)sp * part_stride;
#pragma unroll
  for (int mt = 0; mt < 2; mt++)
#pragma unroll
    for (int jd = 0; jd < 8; jd++)
#pragma unroll
      for (int r = 0; r < 4; r++) {
        int row = qr + mt * 16 + quad * 4 + r;
        int col = h * HD + jd * 16 + l16;
        Od[(long)row * HID + col] = (f16)o[mt][jd][r];
      }
  if (l16 == 0) {
#pragma unroll
    for (int mt = 0; mt < 2; mt++)
#pragma unroll
      for (int r = 0; r < 4; r++) {
        int row = qr + mt * 16 + quad * 4 + r;
        float2 v; v.x = m_run[mt * 4 + r]; v.y = l_run[mt * 4 + r];
        ml[((long)(p0 + sp) * NH + h) * S_LEN + row] = v;
      }
  }
}

// ---------------------------------------------------------------------------
// Combine: out = sum_p w_p O_p (stream1: p0..3, stream2: p4..5), per f16x8 chunk
__global__ void k_combine(const f16* __restrict__ O0, const f16* __restrict__ O1,
                          const f16* __restrict__ O2, const f16* __restrict__ O3,
                          const f16* __restrict__ O4, const f16* __restrict__ O5,
                          const float2* __restrict__ ml, f16* __restrict__ out, int nchunk) {
  int i = blockIdx.x * 256 + threadIdx.x;
  if (i >= nchunk) return;
  int s = i / 384, d8 = i - s * 384, h = d8 >> 4;
  long base = (long)h * S_LEN + s;
  float2 a0 = ml[0 * NH * S_LEN + base];
  float2 a1 = ml[1L * NH * S_LEN + base];
  float2 a2 = ml[2L * NH * S_LEN + base];
  float2 a3 = ml[3L * NH * S_LEN + base];
  float2 a4 = ml[4L * NH * S_LEN + base];
  float2 a5 = ml[5L * NH * S_LEN + base];
  float M1 = fmaxf(fmaxf(a0.x, a1.x), fmaxf(a2.x, a3.x));
  float e0 = __expf(a0.x - M1), e1 = __expf(a1.x - M1), e2 = __expf(a2.x - M1), e3 = __expf(a3.x - M1);
  float L1 = a0.y * e0 + a1.y * e1 + a2.y * e2 + a3.y * e3;
  float w0 = e0 / L1, w1 = e1 / L1, w2 = e2 / L1, w3 = e3 / L1;
  float M2 = fmaxf(a4.x, a5.x);
  float e4 = __expf(a4.x - M2), e5 = __expf(a5.x - M2);
  float L2 = a4.y * e4 + a5.y * e5;
  float w4 = e4 / L2, w5 = e5 / L2;
  f16x8 v0 = ((const f16x8*)O0)[i];
  f16x8 v1 = ((const f16x8*)O1)[i];
  f16x8 v2 = ((const f16x8*)O2)[i];
  f16x8 v3 = ((const f16x8*)O3)[i];
  f16x8 v4 = ((const f16x8*)O4)[i];
  f16x8 v5 = ((const f16x8*)O5)[i];
  f16x8 r;
#pragma unroll
  for (int j = 0; j < 8; j++) {
    float acc = w0 * (float)v0[j] + w1 * (float)v1[j] + w2 * (float)v2[j] + w3 * (float)v3[j]
              + w4 * (float)v4[j] + w5 * (float)v5[j];
    r[j] = (f16)acc;
  }
  ((f16x8*)out)[i] = r;
}

// ---------------------------------------------------------------------------
extern "C" void kernel_launch(void* const* d_in, const int* in_sizes, int n_in,
                              void* d_out, int out_size, void* d_ws, size_t ws_size,
                              hipStream_t stream) {
  const float* hs   = (const float*)d_in[0];
  const float* ip   = (const float*)d_in[1];
  const float* snp  = (const float*)d_in[2];
  const float* csp  = (const float*)d_in[3];
  const float* Wq   = (const float*)d_in[4];
  const float* bq   = (const float*)d_in[5];
  const float* Wk   = (const float*)d_in[6];
  const float* bk   = (const float*)d_in[7];
  const float* Wv   = (const float*)d_in[8];
  const float* bv   = (const float*)d_in[9];
  const float* Wo   = (const float*)d_in[10];
  const float* bo   = (const float*)d_in[11];
  const float* Wkip = (const float*)d_in[12];
  const float* bkip = (const float*)d_in[13];
  const float* Wvip = (const float*)d_in[14];
  const float* bvip = (const float*)d_in[15];
  const float* qs   = (const float*)d_in[16];
  const float* ks   = (const float*)d_in[17];
  float* out = (float*)d_out;

  // sizes (f16 elements)
  const long n1   = 6291456;   // 2048*3072
  const long nW   = 9437184;   // 3072*3072
  const long nip  = 589824;    // 512*1152
  const long nWip = 3538944;   // 3072*1152

  // static layout with lifetime-checked reuse
  const long o_hs   = 0;
  const long o_Wq   = 6291456;
  const long o_Wk   = 15728640;
  const long o_Wv   = 25165824;
  const long o_Wo   = 34603008;
  const long o_ip   = 44040192;
  const long o_Wkip = 44630016;
  const long o_Wvip = 48168960;
  const long o_q    = 51707904;
  const long o_k    = 57999360;
  const long o_v    = 64290816;
  const long o_kip  = 70582272;
  const long o_vip  = 72155136;
  const long o_qrot = 73728000;
  const long o_qnorm= 80019456;
  const long o_Vpip = 87883776;
  const long o_ml   = 89456640;   // float2[6*24*2048]
  const long o_Kps  = o_hs;
  const long o_Op0  = o_Wq;       // p0..p3 stride n1
  const long o_Op4  = o_Wkip;
  const long o_Op5  = o_q;
  const long o_Vps  = o_k;
  const long o_Kpip = o_kip;
  const long o_attn = o_v;

  f16* WS = (f16*)d_ws;
  auto P = [&](long off) { return WS + off; };
  float2* mlp = (float2*)(WS + o_ml);

  // 1) all casts in one launch
  CastArgs ca;
  ca.src[0] = hs;   ca.dst[0] = P(o_hs);   ca.n4[0] = n1 / 4;
  ca.src[1] = ip;   ca.dst[1] = P(o_ip);   ca.n4[1] = nip / 4;
  ca.src[2] = Wq;   ca.dst[2] = P(o_Wq);   ca.n4[2] = nW / 4;
  ca.src[3] = Wk;   ca.dst[3] = P(o_Wk);   ca.n4[3] = nW / 4;
  ca.src[4] = Wv;   ca.dst[4] = P(o_Wv);   ca.n4[4] = nW / 4;
  ca.src[5] = Wo;   ca.dst[5] = P(o_Wo);   ca.n4[5] = nW / 4;
  ca.src[6] = Wkip; ca.dst[6] = P(o_Wkip); ca.n4[6] = nWip / 4;
  ca.src[7] = Wvip; ca.dst[7] = P(o_Wvip); ca.n4[7] = nWip / 4;
  const long total4 = (n1 + nip + 4 * nW + 2 * nWip) / 4;
  k_cvt_all<<<dim3((total4 + 255) / 256), 256, 0, stream>>>(ca, total4);

  // 2) projections
  k_gemm_nt<<<dim3(24, 16, 3), 256, 0, stream>>>(P(o_hs),
      P(o_Wq), P(o_Wk), P(o_Wv), bq, bk, bv,
      P(o_q), P(o_k), P(o_v), 2048, 3072, 3072, 0);
  k_gemm_nt<<<dim3(24, 4, 2), 256, 0, stream>>>(P(o_ip),
      P(o_Wkip), P(o_Wvip), P(o_Wvip), bkip, bvip, bvip,
      P(o_kip), P(o_vip), P(o_vip), 512, 3072, 1152, 0);

  // 3) prep (fused): qprep, krope_pack, rms_pack(ip), vpacks
  k_qprep<<<dim3(49152 / 4), 256, 0, stream>>>(P(o_q), snp, csp, qs, P(o_qrot), P(o_qnorm), 49152);
  k_krope_pack<<<dim3(786432 / 256), 256, 0, stream>>>(P(o_k), snp, csp, P(o_Kps), 2048, 786432);
  k_rms_pack<<<dim3(12288 / 16), 256, 0, stream>>>(P(o_kip), ks, P(o_Kpip), 512, 12288);
  k_vpack<<<dim3(32, 24), 256, 0, stream>>>(P(o_v),   P(o_Vps),  2048);
  k_vpack<<<dim3(8, 24),  256, 0, stream>>>(P(o_vip), P(o_Vpip), 512);

  // 4) flash with split-T (self: 4 splits of 512; ip: 2 splits of 256)
  k_flash2<<<dim3(16, 24, 4), 256, 0, stream>>>(P(o_qrot), P(o_Kps), P(o_Vps),
      P(o_Op0), n1, mlp, 0, 2048, 512);
  k_flash2<<<dim3(16, 24, 2), 256, 0, stream>>>(P(o_qnorm), P(o_Kpip), P(o_Vpip),
      P(o_Op4), o_Op5 - o_Op4, mlp, 4, 512, 256);

  // 5) combine partials -> attn (f16)
  k_combine<<<dim3(786432 / 256), 256, 0, stream>>>(
      P(o_Op0), P(o_Op0 + n1), P(o_Op0 + 2 * n1), P(o_Op0 + 3 * n1),
      P(o_Op4), P(o_Op5), mlp, P(o_attn), 786432);

  // 6) output projection -> fp32 d_out
  k_gemm_nt<<<dim3(24, 16, 1), 256, 0, stream>>>(P(o_attn),
      P(o_Wo), P(o_Wo), P(o_Wo), bo, bo, bo,
      out, out, out, 2048, 3072, 3072, 1);
}